// Round 8
// baseline (744.581 us; speedup 1.0000x reference)
//
#include <hip/hip_runtime.h>
#include <hip/hip_bf16.h>

#define D_ 128
#define L_ 65536
#define C_ 32768
#define E_ 262144

typedef __hip_bfloat16 bf16;
typedef __attribute__((ext_vector_type(8))) short short8;
typedef __attribute__((ext_vector_type(4))) float f32x4;

// flags[0] = 1 if float inputs are fp32 (else bf16); flags[1] = 1 if edge idx int32 (else int64)
__global__ void detect_k(const unsigned short* __restrict__ wmem,
                         const int* __restrict__ li, int* __restrict__ flags) {
    int t = blockIdx.x * 512 + threadIdx.x;
    if (t < 8192) {
        unsigned short h = wmem[2 * t];
        float v = __bfloat162float(*(const bf16*)&h);
        if (!(fabsf(v) < 0.5f)) atomicOr(&flags[0], 1);
    }
    if (t < 2048) {
        if (li[2 * t + 1] != 0) atomicOr(&flags[1], 1);
    }
}

__device__ __forceinline__ void split2(float v, unsigned short& h, unsigned short& l) {
    bf16 bh = __float2bfloat16(v);
    float fh = __bfloat162float(bh);
    bf16 bl = __float2bfloat16(v - fh);
    h = *(unsigned short*)&bh;
    l = *(unsigned short*)&bl;
}

__device__ __forceinline__ float ldf(const void* s, int i, int isf32) {
    return isf32 ? ((const float*)s)[i] : __bfloat162float(((const bf16*)s)[i]);
}

// index fix (int32/int64, clamp) + degree count, both sides in one launch
__global__ void fixdeg_k(const int* __restrict__ ls, const int* __restrict__ cs,
                         int* __restrict__ ld_idx, int* __restrict__ cd_idx,
                         int* __restrict__ ldeg, int* __restrict__ cdeg,
                         const int* __restrict__ flags) {
    int i = blockIdx.x * 256 + threadIdx.x;
    int is32 = flags[1];
    if (i < E_) {
        int v = is32 ? ls[i] : ls[2 * i];
        v = min(max(v, 0), L_ - 1);
        ld_idx[i] = v;
        atomicAdd(&ldeg[v], 1);
    } else {
        int j = i - E_;
        int v = is32 ? cs[j] : cs[2 * j];
        v = min(max(v, 0), C_ - 1);
        cd_idx[j] = v;
        atomicAdd(&cdeg[v], 1);
    }
}

// weights: W[k][n] -> transposed bf16 hi/lo [n][k] packed pool; tail: biases -> fp32
__global__ void cvtwb_k(const void* s0, const void* s1, const void* s2, const void* s3,
                        const void* s4, const void* s5, const void* s6, const void* s7,
                        const void* t0, const void* t1, const void* t2, const void* t3,
                        const void* t4, const void* t5, const void* t6, const void* t7,
                        unsigned short* __restrict__ hi, unsigned short* __restrict__ lo,
                        float* __restrict__ bb, const int* __restrict__ flags) {
    int i = blockIdx.x * 256 + threadIdx.x;  // 181248 total
    int isf = flags[0];
    if (i >= 180224) {
        int j = i - 180224;  // 0..1023
        const void* src;
        switch (j >> 7) {
            case 0: src = t0; break; case 1: src = t1; break;
            case 2: src = t2; break; case 3: src = t3; break;
            case 4: src = t4; break; case 5: src = t5; break;
            case 6: src = t6; break; default: src = t7; break;
        }
        bb[j] = ldf(src, j & 127, isf);
        return;
    }
    const void* src; int K, base;
    if      (i <  16384) { src = s0; K = 128; base = 0; }
    else if (i <  32768) { src = s1; K = 128; base = 16384; }
    else if (i <  49152) { src = s2; K = 128; base = 32768; }
    else if (i <  65536) { src = s3; K = 128; base = 49152; }
    else if (i <  81920) { src = s4; K = 128; base = 65536; }
    else if (i <  98304) { src = s5; K = 128; base = 81920; }
    else if (i < 131072) { src = s6; K = 256; base = 98304; }
    else                 { src = s7; K = 384; base = 131072; }
    int e = i - base;
    int k = e >> 7, n = e & 127;
    float v = ldf(src, e, isf);
    unsigned short h, l;
    split2(v, h, l);
    hi[base + n * K + k] = h;
    lo[base + n * K + k] = l;
}

// broadcast-init embeddings, float4 stores
__global__ void init2_k(const void* __restrict__ lv, const void* __restrict__ cv,
                        float* __restrict__ lemb, float* __restrict__ cemb,
                        const int* __restrict__ flags) {
    int i4 = blockIdx.x * 256 + threadIdx.x;  // float4 id, total (L+C)*32
    int isf = flags[0];
    const void* src; float* dst; int o;
    if (i4 < L_ * 32) { src = lv; dst = lemb; o = i4; }
    else              { src = cv; dst = cemb; o = i4 - L_ * 32; }
    int j = (o & 31) * 4;
    float4 v;
    v.x = ldf(src, j + 0, isf);
    v.y = ldf(src, j + 1, isf);
    v.z = ldf(src, j + 2, isf);
    v.w = ldf(src, j + 3, isf);
    ((float4*)dst)[o] = v;
}

// --- two-level exclusive scans, both sides fused ---
__global__ void scan1b_k(const int* __restrict__ ldeg, const int* __restrict__ cdeg,
                         int* __restrict__ lout, int* __restrict__ cout,
                         int* __restrict__ bsumL, int* __restrict__ bsumC) {
    __shared__ int s[256];
    const int* in; int* out; int* bs; int tile;
    if (blockIdx.x < 256) { in = ldeg; out = lout; bs = bsumL; tile = blockIdx.x; }
    else                  { in = cdeg; out = cout; bs = bsumC; tile = blockIdx.x - 256; }
    int i = tile * 256 + threadIdx.x;
    int v = in[i];
    s[threadIdx.x] = v;
    __syncthreads();
#pragma unroll
    for (int off = 1; off < 256; off <<= 1) {
        int t = (threadIdx.x >= off) ? s[threadIdx.x - off] : 0;
        __syncthreads();
        s[threadIdx.x] += t;
        __syncthreads();
    }
    out[i] = s[threadIdx.x] - v;
    if (threadIdx.x == 255) bs[tile] = s[255];
}

__global__ void scan2b_k(int* __restrict__ bL, int* __restrict__ bC) {
    __shared__ int s[256];
    int* b = blockIdx.x ? bC : bL;
    int nb = blockIdx.x ? 128 : 256;
    int v = (threadIdx.x < nb) ? b[threadIdx.x] : 0;
    s[threadIdx.x] = v;
    __syncthreads();
#pragma unroll
    for (int off = 1; off < 256; off <<= 1) {
        int t = (threadIdx.x >= off) ? s[threadIdx.x - off] : 0;
        __syncthreads();
        s[threadIdx.x] += t;
        __syncthreads();
    }
    if (threadIdx.x < nb) b[threadIdx.x] = s[threadIdx.x] - v;
}

// add block sums, init place cursors, compute invsq = deg ? 1/sqrt(deg) : 0
__global__ void scan3b_k(int* __restrict__ lptr, int* __restrict__ cptr,
                         const int* __restrict__ bsumL, const int* __restrict__ bsumC,
                         int* __restrict__ lcur, int* __restrict__ ccur,
                         const int* __restrict__ ldeg, const int* __restrict__ cdeg,
                         float* __restrict__ invsq_l, float* __restrict__ invsq_c) {
    int b = blockIdx.x, t = threadIdx.x;
    if (b < 256) {
        int i = b * 256 + t;
        int v = lptr[i] + bsumL[b];
        lptr[i] = v; lcur[i] = v;
        int d = ldeg[i];
        invsq_l[i] = d ? rsqrtf((float)d) : 0.0f;
    } else {
        int i = (b - 256) * 256 + t;
        int v = cptr[i] + bsumC[b - 256];
        cptr[i] = v; ccur[i] = v;
        int d = cdeg[i];
        invsq_c[i] = d ? rsqrtf((float)d) : 0.0f;
    }
}

// CSR placement (other endpoint only; norm is separable)
__global__ void place_k(const int* __restrict__ li, const int* __restrict__ ci,
                        int* __restrict__ lcur, int* __restrict__ ccur,
                        int* __restrict__ l_other, int* __restrict__ c_other) {
    int e = blockIdx.x * 256 + threadIdx.x;
    if (e >= E_) return;
    int l = li[e], c = ci[e];
    int p = atomicAdd(&ccur[c], 1);
    c_other[p] = l;
    int q = atomicAdd(&lcur[l], 1);
    l_other[q] = c;
}

// Fused pull-aggregation, both directions: nodes [0,nC) = clause side, rest = literal.
// Wave per node; msgs pre-scaled by producer invsq; dest invsq applied here.
// 4-wide unroll: four independent row fetches in flight (mean deg 4-8).
__global__ __launch_bounds__(256) void gather2_k(
    const int* __restrict__ cptr, const int* __restrict__ cdeg, const int* __restrict__ c_other,
    const float* __restrict__ lmsg, const float* __restrict__ invsq_c, float* __restrict__ caggr,
    const int* __restrict__ lptr, const int* __restrict__ ldeg, const int* __restrict__ l_other,
    const float* __restrict__ cmsg, const float* __restrict__ invsq_l, float* __restrict__ laggr,
    int nC) {
    int node = (blockIdx.x * 256 + threadIdx.x) >> 6;
    int lane = threadIdx.x & 63;
    bool cside = node < nC;
    int j = cside ? node : node - nC;
    const int* ptr = cside ? cptr : lptr;
    const int* dg  = cside ? cdeg : ldeg;
    const int* oth = cside ? c_other : l_other;
    const float* msg = cside ? lmsg : cmsg;
    float sc = (cside ? invsq_c : invsq_l)[j];
    float* out = cside ? caggr : laggr;
    int s = ptr[j], cnt = dg[j];
    float2 a0 = {0.f, 0.f}, a1 = {0.f, 0.f};
    int k = 0;
    for (; k + 4 <= cnt; k += 4) {
        int o0 = oth[s + k], o1 = oth[s + k + 1], o2 = oth[s + k + 2], o3 = oth[s + k + 3];
        const float2 m0 = *(const float2*)&msg[(size_t)o0 * D_ + 2 * lane];
        const float2 m1 = *(const float2*)&msg[(size_t)o1 * D_ + 2 * lane];
        const float2 m2 = *(const float2*)&msg[(size_t)o2 * D_ + 2 * lane];
        const float2 m3 = *(const float2*)&msg[(size_t)o3 * D_ + 2 * lane];
        a0.x += m0.x + m2.x; a0.y += m0.y + m2.y;
        a1.x += m1.x + m3.x; a1.y += m1.y + m3.y;
    }
    for (; k < cnt; k++) {
        int o = oth[s + k];
        const float2 m = *(const float2*)&msg[(size_t)o * D_ + 2 * lane];
        a0.x += m.x; a0.y += m.y;
    }
    a0.x = (a0.x + a1.x) * sc;
    a0.y = (a0.y + a1.y) * sc;
    *(float2*)&out[(size_t)j * D_ + 2 * lane] = a0;
}

// ---------- fused 2-layer MLPs, all three in one launch; 64-row tiles ----------
// blocks [0,nL): l2c on l_cur -> l_msg (scaled by invsq_l)
// blocks [nL,nL+nC): c2l on c_cur -> c_msg (scaled by invsq_c)
// blocks [nL+nC,...): l2l on l_cur with pair-SWAP -> l2lb (unscaled)
// 4 waves = 2x2; wave tile 32x64 = 2x4 mfma_16x16x32 tiles. LDS 33 KB -> 4 blocks/CU.
__global__ __launch_bounds__(256, 4) void mlp3_k(
    const float* __restrict__ l_cur, const float* __restrict__ c_cur,
    const unsigned short* __restrict__ wt_hi, const unsigned short* __restrict__ wt_lo,
    const float* __restrict__ bb,
    const float* __restrict__ invsq_l, const float* __restrict__ invsq_c,
    float* __restrict__ l_msg, float* __restrict__ c_msg, float* __restrict__ l2lb,
    int nL, int nC) {
    __shared__ __align__(16) char smem[33024];
    unsigned short (*a_hi)[40] = (unsigned short(*)[40])(smem);            //  64x40
    unsigned short (*a_lo)[40] = (unsigned short(*)[40])(smem + 5120);     //  64x40
    unsigned short (*b_hi)[40] = (unsigned short(*)[40])(smem + 10240);    // 128x40
    unsigned short (*b_lo)[40] = (unsigned short(*)[40])(smem + 20480);    // 128x40
    unsigned short* h_hi = (unsigned short*)(smem);           // 64x128, aliases tiles
    unsigned short* h_lo = (unsigned short*)(smem + 16384);
    float* scv = (float*)(smem + 32768);                      // 64 floats, non-aliased

    int b = blockIdx.x, seg, tile;
    if (b < nL)           { seg = 0; tile = b; }
    else if (b < nL + nC) { seg = 1; tile = b - nL; }
    else                  { seg = 2; tile = b - nL - nC; }
    const float* A = (seg == 1) ? c_cur : l_cur;
    float* outp = (seg == 0) ? l_msg : (seg == 1) ? c_msg : l2lb;
    const float* invsq = (seg == 0) ? invsq_l : (seg == 1) ? invsq_c : nullptr;
    const unsigned short* W1h = wt_hi + seg * 32768;
    const unsigned short* W1l = wt_lo + seg * 32768;
    const unsigned short* W2h = W1h + 16384;
    const unsigned short* W2l = W1l + 16384;
    const float* b1v = bb + seg * 256;
    const float* b2v = b1v + 128;
    const int swap = (seg == 2);

    const int t = threadIdx.x;
    const int br0 = tile * 64;
    const int w = t >> 6, lane = t & 63;
    const int wr = w >> 1, wc = w & 1;
    const int quad = lane >> 4, cl = lane & 15;

    if (t < 64) scv[t] = invsq ? invsq[br0 + t] : 1.0f;

    f32x4 acc[2][4];
#pragma unroll
    for (int i = 0; i < 2; i++)
#pragma unroll
        for (int j = 0; j < 4; j++) acc[i][j] = (f32x4){0.f, 0.f, 0.f, 0.f};

    // ---- phase 1: h = A @ W1 ----
    for (int kt = 0; kt < 128; kt += 32) {
#pragma unroll
        for (int i = 0; i < 2; i++) {  // A tile: 64 rows x 32 k
            int f = t + 256 * i;
            int r = f >> 3, kq = f & 7;
            int gr = br0 + r;
            if (swap) gr ^= 1;
            const float4 v = *(const float4*)&A[(size_t)gr * D_ + kt + 4 * kq];
            unsigned short h0, l0, h1, l1, h2, l2, h3, l3;
            split2(v.x, h0, l0); split2(v.y, h1, l1);
            split2(v.z, h2, l2); split2(v.w, h3, l3);
            *(ushort4*)&a_hi[r][4 * kq] = make_ushort4(h0, h1, h2, h3);
            *(ushort4*)&a_lo[r][4 * kq] = make_ushort4(l0, l1, l2, l3);
        }
#pragma unroll
        for (int i = 0; i < 4; i++) {  // W1 tile: 128 cols x 32 k
            int f = t + 256 * i;
            int r = f >> 3, kq = f & 7;
            *(ushort4*)&b_hi[r][4 * kq] = *(const ushort4*)&W1h[(size_t)r * 128 + kt + 4 * kq];
            *(ushort4*)&b_lo[r][4 * kq] = *(const ushort4*)&W1l[(size_t)r * 128 + kt + 4 * kq];
        }
        __syncthreads();
        short8 af_h[2], af_l[2];
#pragma unroll
        for (int i = 0; i < 2; i++) {
            int row = 32 * wr + 16 * i + cl;
            af_h[i] = *(const short8*)&a_hi[row][quad * 8];
            af_l[i] = *(const short8*)&a_lo[row][quad * 8];
        }
#pragma unroll
        for (int j = 0; j < 4; j++) {
            int col = 64 * wc + 16 * j + cl;
            short8 bf_h = *(const short8*)&b_hi[col][quad * 8];
            short8 bf_l = *(const short8*)&b_lo[col][quad * 8];
#pragma unroll
            for (int i = 0; i < 2; i++) {
                acc[i][j] = __builtin_amdgcn_mfma_f32_16x16x32_bf16(af_h[i], bf_h, acc[i][j], 0, 0, 0);
                acc[i][j] = __builtin_amdgcn_mfma_f32_16x16x32_bf16(af_h[i], bf_l, acc[i][j], 0, 0, 0);
                acc[i][j] = __builtin_amdgcn_mfma_f32_16x16x32_bf16(af_l[i], bf_h, acc[i][j], 0, 0, 0);
            }
        }
        __syncthreads();
    }
    // h epilogue: bias + relu + split -> swizzled LDS. C/D: col=cl, row=quad*4+reg.
#pragma unroll
    for (int j = 0; j < 4; j++) {
        int col = 64 * wc + 16 * j + cl;  // hidden index k2
        float bv = b1v[col];
        int g = col >> 3, go = col & 7;
#pragma unroll
        for (int i = 0; i < 2; i++) {
            int rloc = 32 * wr + 16 * i + quad * 4;
#pragma unroll
            for (int rg = 0; rg < 4; rg++) {
                float v = fmaxf(acc[i][j][rg] + bv, 0.0f);
                unsigned short hh, ll;
                split2(v, hh, ll);
                int r = rloc + rg;
                int off = r * 128 + ((g ^ (r & 15)) << 3) + go;
                h_hi[off] = hh;
                h_lo[off] = ll;
            }
        }
    }
    __syncthreads();
    // ---- phase 2: out = (h @ W2 + b2) * scv ----
#pragma unroll
    for (int i = 0; i < 2; i++)
#pragma unroll
        for (int j = 0; j < 4; j++) acc[i][j] = (f32x4){0.f, 0.f, 0.f, 0.f};

    for (int kt = 0; kt < 128; kt += 32) {
        short8 af_h[2], af_l[2];
        int gbase = (kt >> 3) + quad;
#pragma unroll
        for (int i = 0; i < 2; i++) {
            int r = 32 * wr + 16 * i + cl;  // r&15 == cl
            int off = r * 128 + ((gbase ^ cl) << 3);
            af_h[i] = *(const short8*)&h_hi[off];
            af_l[i] = *(const short8*)&h_lo[off];
        }
#pragma unroll
        for (int j = 0; j < 4; j++) {
            int col = 64 * wc + 16 * j + cl;
            const short8 bf_h = *(const short8*)&W2h[(size_t)col * 128 + kt + quad * 8];
            const short8 bf_l = *(const short8*)&W2l[(size_t)col * 128 + kt + quad * 8];
#pragma unroll
            for (int i = 0; i < 2; i++) {
                acc[i][j] = __builtin_amdgcn_mfma_f32_16x16x32_bf16(af_h[i], bf_h, acc[i][j], 0, 0, 0);
                acc[i][j] = __builtin_amdgcn_mfma_f32_16x16x32_bf16(af_h[i], bf_l, acc[i][j], 0, 0, 0);
                acc[i][j] = __builtin_amdgcn_mfma_f32_16x16x32_bf16(af_l[i], bf_h, acc[i][j], 0, 0, 0);
            }
        }
    }
#pragma unroll
    for (int j = 0; j < 4; j++) {
        int col = 64 * wc + 16 * j + cl;
        float bv = b2v[col];
#pragma unroll
        for (int i = 0; i < 2; i++) {
            int rloc = 32 * wr + 16 * i + quad * 4;
#pragma unroll
            for (int rg = 0; rg < 4; rg++)
                outp[(size_t)(br0 + rloc + rg) * D_ + col] = (acc[i][j][rg] + bv) * scv[rloc + rg];
        }
    }
}

// ---------- fused update GEMMs; 64-row tiles (LDS 30.7 KB -> ~5 blocks/CU) ----------
// FINAL=0: blocks [0,512) c-update K=256 -> c_nxt; [512,1536) l-update K=384 -> l_nxt.
// FINAL=1: all blocks l-update K=384 -> d_out (fp32 or bf16 per flags[0]).
template <int FINAL>
__global__ __launch_bounds__(256, 4) void update_k(
    const float* __restrict__ l_cur, const float* __restrict__ c_cur,
    const float* __restrict__ laggr, const float* __restrict__ caggr,
    const float* __restrict__ l2lb,
    const unsigned short* __restrict__ wt_hi, const unsigned short* __restrict__ wt_lo,
    const float* __restrict__ bb,
    float* __restrict__ c_nxt, float* __restrict__ l_nxt,
    void* __restrict__ dout, const int* __restrict__ flags) {
    __shared__ unsigned short a_hi[64][40], a_lo[64][40];
    __shared__ unsigned short b_hi[128][40], b_lo[128][40];
    const int t = threadIdx.x;
    int b = blockIdx.x;
    const bool cseg = (!FINAL) && (b < 512);
    const int tile = (FINAL || cseg) ? b : b - 512;
    const int K = cseg ? 256 : 384;
    const float* A0 = cseg ? c_cur : l_cur;
    const float* A1 = cseg ? caggr : laggr;
    const float* A2 = l2lb;
    const unsigned short* Wh = wt_hi + (cseg ? 98304 : 131072);
    const unsigned short* Wl = wt_lo + (cseg ? 98304 : 131072);
    const float* bias = bb + (cseg ? 768 : 896);
    const int br0 = tile * 64;
    const int w = t >> 6, lane = t & 63;
    const int wr = w >> 1, wc = w & 1;
    const int quad = lane >> 4, cl = lane & 15;

    f32x4 acc[2][4];
#pragma unroll
    for (int i = 0; i < 2; i++)
#pragma unroll
        for (int j = 0; j < 4; j++) acc[i][j] = (f32x4){0.f, 0.f, 0.f, 0.f};

    for (int kt = 0; kt < K; kt += 32) {
        const float* As = (kt < 128) ? A0 : (kt < 256) ? A1 : A2;
        const int koff = kt & 127;
#pragma unroll
        for (int i = 0; i < 2; i++) {
            int f = t + 256 * i;
            int r = f >> 3, kq = f & 7;
            const float4 v = *(const float4*)&As[(size_t)(br0 + r) * D_ + koff + 4 * kq];
            unsigned short h0, l0, h1, l1, h2, l2, h3, l3;
            split2(v.x, h0, l0); split2(v.y, h1, l1);
            split2(v.z, h2, l2); split2(v.w, h3, l3);
            *(ushort4*)&a_hi[r][4 * kq] = make_ushort4(h0, h1, h2, h3);
            *(ushort4*)&a_lo[r][4 * kq] = make_ushort4(l0, l1, l2, l3);
        }
#pragma unroll
        for (int i = 0; i < 4; i++) {
            int f = t + 256 * i;
            int r = f >> 3, kq = f & 7;
            *(ushort4*)&b_hi[r][4 * kq] = *(const ushort4*)&Wh[(size_t)r * K + kt + 4 * kq];
            *(ushort4*)&b_lo[r][4 * kq] = *(const ushort4*)&Wl[(size_t)r * K + kt + 4 * kq];
        }
        __syncthreads();
        short8 af_h[2], af_l[2];
#pragma unroll
        for (int i = 0; i < 2; i++) {
            int row = 32 * wr + 16 * i + cl;
            af_h[i] = *(const short8*)&a_hi[row][quad * 8];
            af_l[i] = *(const short8*)&a_lo[row][quad * 8];
        }
#pragma unroll
        for (int j = 0; j < 4; j++) {
            int col = 64 * wc + 16 * j + cl;
            short8 bf_h = *(const short8*)&b_hi[col][quad * 8];
            short8 bf_l = *(const short8*)&b_lo[col][quad * 8];
#pragma unroll
            for (int i = 0; i < 2; i++) {
                acc[i][j] = __builtin_amdgcn_mfma_f32_16x16x32_bf16(af_h[i], bf_h, acc[i][j], 0, 0, 0);
                acc[i][j] = __builtin_amdgcn_mfma_f32_16x16x32_bf16(af_h[i], bf_l, acc[i][j], 0, 0, 0);
                acc[i][j] = __builtin_amdgcn_mfma_f32_16x16x32_bf16(af_l[i], bf_h, acc[i][j], 0, 0, 0);
            }
        }
        __syncthreads();
    }
    const int f32out = FINAL ? flags[0] : 1;
#pragma unroll
    for (int j = 0; j < 4; j++) {
        int col = 64 * wc + 16 * j + cl;
        float bv = bias[col];
#pragma unroll
        for (int i = 0; i < 2; i++) {
            int rbase = br0 + 32 * wr + 16 * i + quad * 4;
#pragma unroll
            for (int rg = 0; rg < 4; rg++) {
                float v = acc[i][j][rg] + bv;
                size_t idx = (size_t)(rbase + rg) * D_ + col;
                if (FINAL) {
                    if (f32out) ((float*)dout)[idx] = v;
                    else        ((bf16*)dout)[idx] = __float2bfloat16(v);
                } else {
                    (cseg ? c_nxt : l_nxt)[idx] = v;
                }
            }
        }
    }
}

extern "C" void kernel_launch(void* const* d_in, const int* in_sizes, int n_in,
                              void* d_out, int out_size, void* d_ws, size_t ws_size,
                              hipStream_t stream) {
    const int* li_raw = (const int*)d_in[0];
    const int* ci_raw = (const int*)d_in[1];

    // ---- workspace layout ----
    float* ws = (float*)d_ws;
    float* lbuf0 = ws;                               // L*D
    float* lbuf1 = lbuf0 + (size_t)L_ * D_;          // L*D
    float* l2lb  = lbuf1 + (size_t)L_ * D_;          // L*D
    float* laggr = l2lb + (size_t)L_ * D_;           // L*D
    float* cbuf0 = laggr + (size_t)L_ * D_;          // C*D
    float* cbuf1 = cbuf0 + (size_t)C_ * D_;          // C*D
    float* caggr = cbuf1 + (size_t)C_ * D_;          // C*D
    float* invsq_l = caggr + (size_t)C_ * D_;        // L
    float* invsq_c = invsq_l + L_;                   // C
    float* bb    = invsq_c + C_;                     // 1024 bias floats
    unsigned short* wt_hi = (unsigned short*)(bb + 1024);   // 180224 ushorts
    unsigned short* wt_lo = wt_hi + 180224;                 // 180224 ushorts
    int*   li    = (int*)(wt_lo + 180224);           // E
    int*   ci    = li + E_;                          // E
    int*   l_other = ci + E_;                        // E
    int*   c_other = l_other + E_;                   // E
    int*   ldegi = c_other + E_;                     // L
    int*   cdegi = ldegi + L_;                       // C
    int*   lptr  = cdegi + C_;                       // L
    int*   cptr  = lptr + L_;                        // C
    int*   lcur  = cptr + C_;                        // L
    int*   ccur  = lcur + L_;                        // C
    int*   bsumL = ccur + C_;                        // 256
    int*   bsumC = bsumL + 256;                      // 128
    int*   flags = bsumC + 128;                      // 2

    // --- dtype detection (device-side, graph-safe) ---
    hipMemsetAsync(flags, 0, 2 * sizeof(int), stream);
    detect_k<<<16, 512, 0, stream>>>((const unsigned short*)d_in[4], li_raw, flags);

    // --- idx fix + degrees (one launch) ---
    hipMemsetAsync(ldegi, 0, (size_t)(L_ + C_) * sizeof(int), stream);
    fixdeg_k<<<2 * E_ / 256, 256, 0, stream>>>(li_raw, ci_raw, li, ci, ldegi, cdegi, flags);

    // --- weight split + bias conversion (one launch) ---
    cvtwb_k<<<708, 256, 0, stream>>>(d_in[4], d_in[6], d_in[8], d_in[10], d_in[12],
                                     d_in[14], d_in[16], d_in[18],
                                     d_in[5], d_in[7], d_in[9], d_in[11], d_in[13],
                                     d_in[15], d_in[17], d_in[19], wt_hi, wt_lo, bb, flags);

    // --- CSR build ---
    scan1b_k<<<384, 256, 0, stream>>>(ldegi, cdegi, lptr, cptr, bsumL, bsumC);
    scan2b_k<<<2, 256, 0, stream>>>(bsumL, bsumC);
    scan3b_k<<<384, 256, 0, stream>>>(lptr, cptr, bsumL, bsumC, lcur, ccur,
                                      ldegi, cdegi, invsq_l, invsq_c);
    place_k<<<E_ / 256, 256, 0, stream>>>(li, ci, lcur, ccur, l_other, c_other);

    // --- broadcast-init embeddings (float4) ---
    init2_k<<<(L_ + C_) * 32 / 256, 256, 0, stream>>>(d_in[2], d_in[3], lbuf0, cbuf0, flags);

    float* l_cur = lbuf0; float* l_nxt = lbuf1;
    float* c_cur = cbuf0; float* c_nxt = cbuf1;

    const int nL = L_ / 64, nC = C_ / 64;  // 64-row tiles
    for (int it = 0; it < 3; it++) {
        mlp3_k<<<2 * nL + nC, 256, 0, stream>>>(
            l_cur, c_cur, wt_hi, wt_lo, bb, invsq_l, invsq_c,
            l_nxt, c_nxt, l2lb, nL, nC);
        gather2_k<<<(C_ + L_) / 4, 256, 0, stream>>>(
            cptr, cdegi, c_other, l_nxt, invsq_c, caggr,
            lptr, ldegi, l_other, c_nxt, invsq_l, laggr, C_);
        update_k<0><<<1536, 256, 0, stream>>>(
            l_cur, c_cur, laggr, caggr, l2lb, wt_hi, wt_lo, bb,
            c_nxt, l_nxt, nullptr, flags);
        float* tmp = l_cur; l_cur = l_nxt; l_nxt = tmp;
        tmp = c_cur; c_cur = c_nxt; c_nxt = tmp;
    }
    // --- final iteration: c-update dead -> skip l2c MLP, c-gather, c-update;
    //     fuse output dtype conversion into the l-update epilogue ---
    mlp3_k<<<nC + nL, 256, 0, stream>>>(
        l_cur, c_cur, wt_hi, wt_lo, bb, invsq_l, invsq_c,
        l_nxt, c_nxt, l2lb, 0, nC);
    gather2_k<<<L_ / 4, 256, 0, stream>>>(
        cptr, cdegi, c_other, l_nxt, invsq_c, caggr,
        lptr, ldegi, l_other, c_nxt, invsq_l, laggr, 0);
    update_k<1><<<1024, 256, 0, stream>>>(
        l_cur, c_cur, laggr, caggr, l2lb, wt_hi, wt_lo, bb,
        nullptr, nullptr, d_out, flags);
}

// Round 9
// 688.400 us; speedup vs baseline: 1.0816x; 1.0816x over previous
//
#include <hip/hip_runtime.h>
#include <hip/hip_bf16.h>

#define D_ 128
#define L_ 65536
#define C_ 32768
#define E_ 262144

typedef __hip_bfloat16 bf16;
typedef __attribute__((ext_vector_type(8))) short short8;
typedef __attribute__((ext_vector_type(4))) float f32x4;

// flags[0] = 1 if float inputs are fp32 (else bf16); flags[1] = 1 if edge idx int32 (else int64)
__global__ void detect_k(const unsigned short* __restrict__ wmem,
                         const int* __restrict__ li, int* __restrict__ flags) {
    int t = blockIdx.x * 512 + threadIdx.x;
    if (t < 8192) {
        unsigned short h = wmem[2 * t];
        float v = __bfloat162float(*(const bf16*)&h);
        if (!(fabsf(v) < 0.5f)) atomicOr(&flags[0], 1);
    }
    if (t < 2048) {
        if (li[2 * t + 1] != 0) atomicOr(&flags[1], 1);
    }
}

__device__ __forceinline__ void split2(float v, unsigned short& h, unsigned short& l) {
    bf16 bh = __float2bfloat16(v);
    float fh = __bfloat162float(bh);
    bf16 bl = __float2bfloat16(v - fh);
    h = *(unsigned short*)&bh;
    l = *(unsigned short*)&bl;
}

__device__ __forceinline__ float ldf(const void* s, int i, int isf32) {
    return isf32 ? ((const float*)s)[i] : __bfloat162float(((const bf16*)s)[i]);
}

// index fix (int32/int64, clamp) + degree count, both sides in one launch
__global__ void fixdeg_k(const int* __restrict__ ls, const int* __restrict__ cs,
                         int* __restrict__ ld_idx, int* __restrict__ cd_idx,
                         int* __restrict__ ldeg, int* __restrict__ cdeg,
                         const int* __restrict__ flags) {
    int i = blockIdx.x * 256 + threadIdx.x;
    int is32 = flags[1];
    if (i < E_) {
        int v = is32 ? ls[i] : ls[2 * i];
        v = min(max(v, 0), L_ - 1);
        ld_idx[i] = v;
        atomicAdd(&ldeg[v], 1);
    } else {
        int j = i - E_;
        int v = is32 ? cs[j] : cs[2 * j];
        v = min(max(v, 0), C_ - 1);
        cd_idx[j] = v;
        atomicAdd(&cdeg[v], 1);
    }
}

// weights: W[k][n] -> transposed bf16 hi/lo [n][k] packed pool; tail: biases -> fp32
__global__ void cvtwb_k(const void* s0, const void* s1, const void* s2, const void* s3,
                        const void* s4, const void* s5, const void* s6, const void* s7,
                        const void* t0, const void* t1, const void* t2, const void* t3,
                        const void* t4, const void* t5, const void* t6, const void* t7,
                        unsigned short* __restrict__ hi, unsigned short* __restrict__ lo,
                        float* __restrict__ bb, const int* __restrict__ flags) {
    int i = blockIdx.x * 256 + threadIdx.x;  // 181248 total
    int isf = flags[0];
    if (i >= 180224) {
        int j = i - 180224;  // 0..1023
        const void* src;
        switch (j >> 7) {
            case 0: src = t0; break; case 1: src = t1; break;
            case 2: src = t2; break; case 3: src = t3; break;
            case 4: src = t4; break; case 5: src = t5; break;
            case 6: src = t6; break; default: src = t7; break;
        }
        bb[j] = ldf(src, j & 127, isf);
        return;
    }
    const void* src; int K, base;
    if      (i <  16384) { src = s0; K = 128; base = 0; }
    else if (i <  32768) { src = s1; K = 128; base = 16384; }
    else if (i <  49152) { src = s2; K = 128; base = 32768; }
    else if (i <  65536) { src = s3; K = 128; base = 49152; }
    else if (i <  81920) { src = s4; K = 128; base = 65536; }
    else if (i <  98304) { src = s5; K = 128; base = 81920; }
    else if (i < 131072) { src = s6; K = 256; base = 98304; }
    else                 { src = s7; K = 384; base = 131072; }
    int e = i - base;
    int k = e >> 7, n = e & 127;
    float v = ldf(src, e, isf);
    unsigned short h, l;
    split2(v, h, l);
    hi[base + n * K + k] = h;
    lo[base + n * K + k] = l;
}

// broadcast-init embeddings, float4 stores
__global__ void init2_k(const void* __restrict__ lv, const void* __restrict__ cv,
                        float* __restrict__ lemb, float* __restrict__ cemb,
                        const int* __restrict__ flags) {
    int i4 = blockIdx.x * 256 + threadIdx.x;  // float4 id, total (L+C)*32
    int isf = flags[0];
    const void* src; float* dst; int o;
    if (i4 < L_ * 32) { src = lv; dst = lemb; o = i4; }
    else              { src = cv; dst = cemb; o = i4 - L_ * 32; }
    int j = (o & 31) * 4;
    float4 v;
    v.x = ldf(src, j + 0, isf);
    v.y = ldf(src, j + 1, isf);
    v.z = ldf(src, j + 2, isf);
    v.w = ldf(src, j + 3, isf);
    ((float4*)dst)[o] = v;
}

// --- two-level exclusive scans, both sides fused ---
__global__ void scan1b_k(const int* __restrict__ ldeg, const int* __restrict__ cdeg,
                         int* __restrict__ lout, int* __restrict__ cout,
                         int* __restrict__ bsumL, int* __restrict__ bsumC) {
    __shared__ int s[256];
    const int* in; int* out; int* bs; int tile;
    if (blockIdx.x < 256) { in = ldeg; out = lout; bs = bsumL; tile = blockIdx.x; }
    else                  { in = cdeg; out = cout; bs = bsumC; tile = blockIdx.x - 256; }
    int i = tile * 256 + threadIdx.x;
    int v = in[i];
    s[threadIdx.x] = v;
    __syncthreads();
#pragma unroll
    for (int off = 1; off < 256; off <<= 1) {
        int t = (threadIdx.x >= off) ? s[threadIdx.x - off] : 0;
        __syncthreads();
        s[threadIdx.x] += t;
        __syncthreads();
    }
    out[i] = s[threadIdx.x] - v;
    if (threadIdx.x == 255) bs[tile] = s[255];
}

__global__ void scan2b_k(int* __restrict__ bL, int* __restrict__ bC) {
    __shared__ int s[256];
    int* b = blockIdx.x ? bC : bL;
    int nb = blockIdx.x ? 128 : 256;
    int v = (threadIdx.x < nb) ? b[threadIdx.x] : 0;
    s[threadIdx.x] = v;
    __syncthreads();
#pragma unroll
    for (int off = 1; off < 256; off <<= 1) {
        int t = (threadIdx.x >= off) ? s[threadIdx.x - off] : 0;
        __syncthreads();
        s[threadIdx.x] += t;
        __syncthreads();
    }
    if (threadIdx.x < nb) b[threadIdx.x] = s[threadIdx.x] - v;
}

// add block sums, init place cursors, compute invsq = deg ? 1/sqrt(deg) : 0
__global__ void scan3b_k(int* __restrict__ lptr, int* __restrict__ cptr,
                         const int* __restrict__ bsumL, const int* __restrict__ bsumC,
                         int* __restrict__ lcur, int* __restrict__ ccur,
                         const int* __restrict__ ldeg, const int* __restrict__ cdeg,
                         float* __restrict__ invsq_l, float* __restrict__ invsq_c) {
    int b = blockIdx.x, t = threadIdx.x;
    if (b < 256) {
        int i = b * 256 + t;
        int v = lptr[i] + bsumL[b];
        lptr[i] = v; lcur[i] = v;
        int d = ldeg[i];
        invsq_l[i] = d ? rsqrtf((float)d) : 0.0f;
    } else {
        int i = (b - 256) * 256 + t;
        int v = cptr[i] + bsumC[b - 256];
        cptr[i] = v; ccur[i] = v;
        int d = cdeg[i];
        invsq_c[i] = d ? rsqrtf((float)d) : 0.0f;
    }
}

// CSR placement (other endpoint only; norm is separable)
__global__ void place_k(const int* __restrict__ li, const int* __restrict__ ci,
                        int* __restrict__ lcur, int* __restrict__ ccur,
                        int* __restrict__ l_other, int* __restrict__ c_other) {
    int e = blockIdx.x * 256 + threadIdx.x;
    if (e >= E_) return;
    int l = li[e], c = ci[e];
    int p = atomicAdd(&ccur[c], 1);
    c_other[p] = l;
    int q = atomicAdd(&lcur[l], 1);
    l_other[q] = c;
}

// Fused pull-aggregation, both directions. Messages are bf16 (row = 64 dwords);
// each lane loads one dword (2 bf16), accumulates fp32, dest invsq applied at end.
__global__ __launch_bounds__(256) void gather2_k(
    const int* __restrict__ cptr, const int* __restrict__ cdeg, const int* __restrict__ c_other,
    const unsigned int* __restrict__ lmsg, const float* __restrict__ invsq_c, float* __restrict__ caggr,
    const int* __restrict__ lptr, const int* __restrict__ ldeg, const int* __restrict__ l_other,
    const unsigned int* __restrict__ cmsg, const float* __restrict__ invsq_l, float* __restrict__ laggr,
    int nC) {
    int node = (blockIdx.x * 256 + threadIdx.x) >> 6;
    int lane = threadIdx.x & 63;
    bool cside = node < nC;
    int j = cside ? node : node - nC;
    const int* ptr = cside ? cptr : lptr;
    const int* dg  = cside ? cdeg : ldeg;
    const int* oth = cside ? c_other : l_other;
    const unsigned int* msg = cside ? lmsg : cmsg;
    float sc = (cside ? invsq_c : invsq_l)[j];
    float* out = cside ? caggr : laggr;
    int s = ptr[j], cnt = dg[j];
    float2 a0 = {0.f, 0.f}, a1 = {0.f, 0.f};
    int k = 0;
    for (; k + 4 <= cnt; k += 4) {
        int o0 = oth[s + k], o1 = oth[s + k + 1], o2 = oth[s + k + 2], o3 = oth[s + k + 3];
        unsigned int u0 = msg[(size_t)o0 * 64 + lane];
        unsigned int u1 = msg[(size_t)o1 * 64 + lane];
        unsigned int u2 = msg[(size_t)o2 * 64 + lane];
        unsigned int u3 = msg[(size_t)o3 * 64 + lane];
        a0.x += __uint_as_float(u0 << 16) + __uint_as_float(u2 << 16);
        a0.y += __uint_as_float(u0 & 0xffff0000u) + __uint_as_float(u2 & 0xffff0000u);
        a1.x += __uint_as_float(u1 << 16) + __uint_as_float(u3 << 16);
        a1.y += __uint_as_float(u1 & 0xffff0000u) + __uint_as_float(u3 & 0xffff0000u);
    }
    for (; k < cnt; k++) {
        int o = oth[s + k];
        unsigned int u = msg[(size_t)o * 64 + lane];
        a0.x += __uint_as_float(u << 16);
        a0.y += __uint_as_float(u & 0xffff0000u);
    }
    a0.x = (a0.x + a1.x) * sc;
    a0.y = (a0.y + a1.y) * sc;
    *(float2*)&out[(size_t)j * D_ + 2 * lane] = a0;
}

// ---------- fused 2-layer MLPs, all three in one launch; 128-row tiles ----------
// blocks [0,nL): l2c on l_cur -> l_msg (scaled by invsq_l)
// blocks [nL,nL+nC): c2l on c_cur -> c_msg (scaled by invsq_c)
// blocks [nL+nC,...): l2l on l_cur with pair-SWAP -> l2lb (unscaled)
// Outputs stored as bf16 (consumed by gather / l-update A2).
__global__ __launch_bounds__(256, 2) void mlp3_k(
    const float* __restrict__ l_cur, const float* __restrict__ c_cur,
    const unsigned short* __restrict__ wt_hi, const unsigned short* __restrict__ wt_lo,
    const float* __restrict__ bb,
    const float* __restrict__ invsq_l, const float* __restrict__ invsq_c,
    bf16* __restrict__ l_msg, bf16* __restrict__ c_msg, bf16* __restrict__ l2lb,
    int nL, int nC) {
    __shared__ char smem[66048];
    unsigned short (*a_hi)[40] = (unsigned short(*)[40])(smem);
    unsigned short (*a_lo)[40] = (unsigned short(*)[40])(smem + 10240);
    unsigned short (*b_hi)[40] = (unsigned short(*)[40])(smem + 20480);
    unsigned short (*b_lo)[40] = (unsigned short(*)[40])(smem + 30720);
    unsigned short* h_hi = (unsigned short*)(smem);          // phase 2 aliases tiles
    unsigned short* h_lo = (unsigned short*)(smem + 32768);
    float* scv = (float*)(smem + 65536);                     // 128 floats, non-aliased

    int b = blockIdx.x, seg, tile;
    if (b < nL)           { seg = 0; tile = b; }
    else if (b < nL + nC) { seg = 1; tile = b - nL; }
    else                  { seg = 2; tile = b - nL - nC; }
    const float* A = (seg == 1) ? c_cur : l_cur;
    bf16* outp = (seg == 0) ? l_msg : (seg == 1) ? c_msg : l2lb;
    const float* invsq = (seg == 0) ? invsq_l : (seg == 1) ? invsq_c : nullptr;
    const unsigned short* W1h = wt_hi + seg * 32768;
    const unsigned short* W1l = wt_lo + seg * 32768;
    const unsigned short* W2h = W1h + 16384;
    const unsigned short* W2l = W1l + 16384;
    const float* b1v = bb + seg * 256;
    const float* b2v = b1v + 128;
    const int swap = (seg == 2);

    const int t = threadIdx.x;
    const int br0 = tile * 128;
    const int w = t >> 6, lane = t & 63;
    const int wr = w >> 1, wc = w & 1;
    const int quad = lane >> 4, cl = lane & 15;

    if (t < 128) scv[t] = invsq ? invsq[br0 + t] : 1.0f;

    f32x4 acc[4][4];
#pragma unroll
    for (int i = 0; i < 4; i++)
#pragma unroll
        for (int j = 0; j < 4; j++) acc[i][j] = (f32x4){0.f, 0.f, 0.f, 0.f};

    // ---- phase 1: h = A @ W1 ----
    for (int kt = 0; kt < 128; kt += 32) {
#pragma unroll
        for (int i = 0; i < 4; i++) {
            int f = t + 256 * i;
            int r = f >> 3, kq = f & 7;
            int gr = br0 + r;
            if (swap) gr ^= 1;
            const float4 v = *(const float4*)&A[(size_t)gr * D_ + kt + 4 * kq];
            unsigned short h0, l0, h1, l1, h2, l2, h3, l3;
            split2(v.x, h0, l0); split2(v.y, h1, l1);
            split2(v.z, h2, l2); split2(v.w, h3, l3);
            *(ushort4*)&a_hi[r][4 * kq] = make_ushort4(h0, h1, h2, h3);
            *(ushort4*)&a_lo[r][4 * kq] = make_ushort4(l0, l1, l2, l3);
            *(ushort4*)&b_hi[r][4 * kq] = *(const ushort4*)&W1h[(size_t)r * 128 + kt + 4 * kq];
            *(ushort4*)&b_lo[r][4 * kq] = *(const ushort4*)&W1l[(size_t)r * 128 + kt + 4 * kq];
        }
        __syncthreads();
        short8 af_h[4], af_l[4];
#pragma unroll
        for (int i = 0; i < 4; i++) {
            int row = 64 * wr + 16 * i + cl;
            af_h[i] = *(const short8*)&a_hi[row][quad * 8];
            af_l[i] = *(const short8*)&a_lo[row][quad * 8];
        }
#pragma unroll
        for (int j = 0; j < 4; j++) {
            int col = 64 * wc + 16 * j + cl;
            short8 bf_h = *(const short8*)&b_hi[col][quad * 8];
            short8 bf_l = *(const short8*)&b_lo[col][quad * 8];
#pragma unroll
            for (int i = 0; i < 4; i++) {
                acc[i][j] = __builtin_amdgcn_mfma_f32_16x16x32_bf16(af_h[i], bf_h, acc[i][j], 0, 0, 0);
                acc[i][j] = __builtin_amdgcn_mfma_f32_16x16x32_bf16(af_h[i], bf_l, acc[i][j], 0, 0, 0);
                acc[i][j] = __builtin_amdgcn_mfma_f32_16x16x32_bf16(af_l[i], bf_h, acc[i][j], 0, 0, 0);
            }
        }
        __syncthreads();
    }
    // h epilogue: bias + relu + split -> swizzled LDS. C/D: col=cl, row=quad*4+reg.
#pragma unroll
    for (int j = 0; j < 4; j++) {
        int col = 64 * wc + 16 * j + cl;
        float bv = b1v[col];
        int g = col >> 3, go = col & 7;
#pragma unroll
        for (int i = 0; i < 4; i++) {
            int rloc = 64 * wr + 16 * i + quad * 4;
#pragma unroll
            for (int rg = 0; rg < 4; rg++) {
                float v = fmaxf(acc[i][j][rg] + bv, 0.0f);
                unsigned short hh, ll;
                split2(v, hh, ll);
                int r = rloc + rg;
                int off = r * 128 + ((g ^ (r & 15)) << 3) + go;
                h_hi[off] = hh;
                h_lo[off] = ll;
            }
        }
    }
    __syncthreads();
    // ---- phase 2: out = (h @ W2 + b2) * scv -> bf16 ----
#pragma unroll
    for (int i = 0; i < 4; i++)
#pragma unroll
        for (int j = 0; j < 4; j++) acc[i][j] = (f32x4){0.f, 0.f, 0.f, 0.f};

    for (int kt = 0; kt < 128; kt += 32) {
        short8 af_h[4], af_l[4];
        int gbase = (kt >> 3) + quad;
#pragma unroll
        for (int i = 0; i < 4; i++) {
            int r = 64 * wr + 16 * i + cl;
            int off = r * 128 + ((gbase ^ cl) << 3);
            af_h[i] = *(const short8*)&h_hi[off];
            af_l[i] = *(const short8*)&h_lo[off];
        }
#pragma unroll
        for (int j = 0; j < 4; j++) {
            int col = 64 * wc + 16 * j + cl;
            const short8 bf_h = *(const short8*)&W2h[(size_t)col * 128 + kt + quad * 8];
            const short8 bf_l = *(const short8*)&W2l[(size_t)col * 128 + kt + quad * 8];
#pragma unroll
            for (int i = 0; i < 4; i++) {
                acc[i][j] = __builtin_amdgcn_mfma_f32_16x16x32_bf16(af_h[i], bf_h, acc[i][j], 0, 0, 0);
                acc[i][j] = __builtin_amdgcn_mfma_f32_16x16x32_bf16(af_h[i], bf_l, acc[i][j], 0, 0, 0);
                acc[i][j] = __builtin_amdgcn_mfma_f32_16x16x32_bf16(af_l[i], bf_h, acc[i][j], 0, 0, 0);
            }
        }
    }
#pragma unroll
    for (int j = 0; j < 4; j++) {
        int col = 64 * wc + 16 * j + cl;
        float bv = b2v[col];
#pragma unroll
        for (int i = 0; i < 4; i++) {
            int rloc = 64 * wr + 16 * i + quad * 4;
#pragma unroll
            for (int rg = 0; rg < 4; rg++)
                outp[(size_t)(br0 + rloc + rg) * D_ + col] =
                    __float2bfloat16((acc[i][j][rg] + bv) * scv[rloc + rg]);
        }
    }
}

// ---------- fused update GEMMs; 128-row tiles ----------
// FINAL=0: blocks [0,256) c-update K=256 -> c_nxt; [256,768) l-update K=384 -> l_nxt.
// FINAL=1: all blocks l-update K=384 -> d_out (fp32 or bf16 per flags[0]).
// A2 (l2l messages) is bf16 -> a_lo==0 for kt>=256: skip the Al*Bh MFMA there.
template <int FINAL>
__global__ __launch_bounds__(256, 2) void update_k(
    const float* __restrict__ l_cur, const float* __restrict__ c_cur,
    const float* __restrict__ laggr, const float* __restrict__ caggr,
    const bf16* __restrict__ l2lb,
    const unsigned short* __restrict__ wt_hi, const unsigned short* __restrict__ wt_lo,
    const float* __restrict__ bb,
    float* __restrict__ c_nxt, float* __restrict__ l_nxt,
    void* __restrict__ dout, const int* __restrict__ flags) {
    __shared__ unsigned short a_hi[128][40], a_lo[128][40];
    __shared__ unsigned short b_hi[128][40], b_lo[128][40];
    const int t = threadIdx.x;
    int b = blockIdx.x;
    const bool cseg = (!FINAL) && (b < 256);
    const int tile = (FINAL || cseg) ? b : b - 256;
    const int K = cseg ? 256 : 384;
    const float* A0 = cseg ? c_cur : l_cur;
    const float* A1 = cseg ? caggr : laggr;
    const unsigned short* Wh = wt_hi + (cseg ? 98304 : 131072);
    const unsigned short* Wl = wt_lo + (cseg ? 98304 : 131072);
    const float* bias = bb + (cseg ? 768 : 896);
    const int br0 = tile * 128;
    const int w = t >> 6, lane = t & 63;
    const int wr = w >> 1, wc = w & 1;
    const int quad = lane >> 4, cl = lane & 15;

    f32x4 acc[4][4];
#pragma unroll
    for (int i = 0; i < 4; i++)
#pragma unroll
        for (int j = 0; j < 4; j++) acc[i][j] = (f32x4){0.f, 0.f, 0.f, 0.f};

    for (int kt = 0; kt < K; kt += 32) {
        const bool haslo = (kt < 256);
        const int koff = kt & 127;
#pragma unroll
        for (int i = 0; i < 4; i++) {
            int f = t + 256 * i;
            int r = f >> 3, kq = f & 7;
            if (haslo) {
                const float* As = (kt < 128) ? A0 : A1;
                const float4 v = *(const float4*)&As[(size_t)(br0 + r) * D_ + koff + 4 * kq];
                unsigned short h0, l0, h1, l1, h2, l2, h3, l3;
                split2(v.x, h0, l0); split2(v.y, h1, l1);
                split2(v.z, h2, l2); split2(v.w, h3, l3);
                *(ushort4*)&a_hi[r][4 * kq] = make_ushort4(h0, h1, h2, h3);
                *(ushort4*)&a_lo[r][4 * kq] = make_ushort4(l0, l1, l2, l3);
            } else {
                *(ushort4*)&a_hi[r][4 * kq] =
                    *(const ushort4*)&l2lb[(size_t)(br0 + r) * D_ + koff + 4 * kq];
            }
            *(ushort4*)&b_hi[r][4 * kq] = *(const ushort4*)&Wh[(size_t)r * K + kt + 4 * kq];
            *(ushort4*)&b_lo[r][4 * kq] = *(const ushort4*)&Wl[(size_t)r * K + kt + 4 * kq];
        }
        __syncthreads();
        short8 af_h[4], af_l[4];
#pragma unroll
        for (int i = 0; i < 4; i++) {
            int row = 64 * wr + 16 * i + cl;
            af_h[i] = *(const short8*)&a_hi[row][quad * 8];
            if (haslo) af_l[i] = *(const short8*)&a_lo[row][quad * 8];
        }
#pragma unroll
        for (int j = 0; j < 4; j++) {
            int col = 64 * wc + 16 * j + cl;
            short8 bf_h = *(const short8*)&b_hi[col][quad * 8];
            short8 bf_l = *(const short8*)&b_lo[col][quad * 8];
#pragma unroll
            for (int i = 0; i < 4; i++) {
                acc[i][j] = __builtin_amdgcn_mfma_f32_16x16x32_bf16(af_h[i], bf_h, acc[i][j], 0, 0, 0);
                acc[i][j] = __builtin_amdgcn_mfma_f32_16x16x32_bf16(af_h[i], bf_l, acc[i][j], 0, 0, 0);
                if (haslo)
                    acc[i][j] = __builtin_amdgcn_mfma_f32_16x16x32_bf16(af_l[i], bf_h, acc[i][j], 0, 0, 0);
            }
        }
        __syncthreads();
    }
    const int f32out = FINAL ? flags[0] : 1;
#pragma unroll
    for (int j = 0; j < 4; j++) {
        int col = 64 * wc + 16 * j + cl;
        float bv = bias[col];
#pragma unroll
        for (int i = 0; i < 4; i++) {
            int rbase = br0 + 64 * wr + 16 * i + quad * 4;
#pragma unroll
            for (int rg = 0; rg < 4; rg++) {
                float v = acc[i][j][rg] + bv;
                size_t idx = (size_t)(rbase + rg) * D_ + col;
                if (FINAL) {
                    if (f32out) ((float*)dout)[idx] = v;
                    else        ((bf16*)dout)[idx] = __float2bfloat16(v);
                } else {
                    (cseg ? c_nxt : l_nxt)[idx] = v;
                }
            }
        }
    }
}

extern "C" void kernel_launch(void* const* d_in, const int* in_sizes, int n_in,
                              void* d_out, int out_size, void* d_ws, size_t ws_size,
                              hipStream_t stream) {
    const int* li_raw = (const int*)d_in[0];
    const int* ci_raw = (const int*)d_in[1];

    // ---- workspace layout ----
    float* ws = (float*)d_ws;
    float* lbuf0 = ws;                               // L*D
    float* lbuf1 = lbuf0 + (size_t)L_ * D_;          // L*D  (doubles as bf16 l_msg)
    float* l2lb  = lbuf1 + (size_t)L_ * D_;          // L*D  (bf16 l2l messages)
    float* laggr = l2lb + (size_t)L_ * D_;           // L*D
    float* cbuf0 = laggr + (size_t)L_ * D_;          // C*D
    float* cbuf1 = cbuf0 + (size_t)C_ * D_;          // C*D  (doubles as bf16 c_msg)
    float* caggr = cbuf1 + (size_t)C_ * D_;          // C*D
    float* invsq_l = caggr + (size_t)C_ * D_;        // L
    float* invsq_c = invsq_l + L_;                   // C
    float* bb    = invsq_c + C_;                     // 1024 bias floats
    unsigned short* wt_hi = (unsigned short*)(bb + 1024);   // 180224 ushorts
    unsigned short* wt_lo = wt_hi + 180224;                 // 180224 ushorts
    int*   li    = (int*)(wt_lo + 180224);           // E
    int*   ci    = li + E_;                          // E
    int*   l_other = ci + E_;                        // E
    int*   c_other = l_other + E_;                   // E
    int*   ldegi = c_other + E_;                     // L
    int*   cdegi = ldegi + L_;                       // C
    int*   lptr  = cdegi + C_;                       // L
    int*   cptr  = lptr + L_;                        // C
    int*   lcur  = cptr + C_;                        // L
    int*   ccur  = lcur + L_;                        // C
    int*   bsumL = ccur + C_;                        // 256
    int*   bsumC = bsumL + 256;                      // 128
    int*   flags = bsumC + 128;                      // 2

    // --- dtype detection (device-side, graph-safe) ---
    hipMemsetAsync(flags, 0, 2 * sizeof(int), stream);
    detect_k<<<16, 512, 0, stream>>>((const unsigned short*)d_in[4], li_raw, flags);

    // --- idx fix + degrees (one launch) ---
    hipMemsetAsync(ldegi, 0, (size_t)(L_ + C_) * sizeof(int), stream);
    fixdeg_k<<<2 * E_ / 256, 256, 0, stream>>>(li_raw, ci_raw, li, ci, ldegi, cdegi, flags);

    // --- weight split + bias conversion (one launch) ---
    cvtwb_k<<<708, 256, 0, stream>>>(d_in[4], d_in[6], d_in[8], d_in[10], d_in[12],
                                     d_in[14], d_in[16], d_in[18],
                                     d_in[5], d_in[7], d_in[9], d_in[11], d_in[13],
                                     d_in[15], d_in[17], d_in[19], wt_hi, wt_lo, bb, flags);

    // --- CSR build ---
    scan1b_k<<<384, 256, 0, stream>>>(ldegi, cdegi, lptr, cptr, bsumL, bsumC);
    scan2b_k<<<2, 256, 0, stream>>>(bsumL, bsumC);
    scan3b_k<<<384, 256, 0, stream>>>(lptr, cptr, bsumL, bsumC, lcur, ccur,
                                      ldegi, cdegi, invsq_l, invsq_c);
    place_k<<<E_ / 256, 256, 0, stream>>>(li, ci, lcur, ccur, l_other, c_other);

    // --- broadcast-init embeddings (float4) ---
    init2_k<<<(L_ + C_) * 32 / 256, 256, 0, stream>>>(d_in[2], d_in[3], lbuf0, cbuf0, flags);

    float* l_cur = lbuf0; float* l_nxt = lbuf1;
    float* c_cur = cbuf0; float* c_nxt = cbuf1;

    const int nL = L_ / 128, nC = C_ / 128;
    for (int it = 0; it < 3; it++) {
        mlp3_k<<<2 * nL + nC, 256, 0, stream>>>(
            l_cur, c_cur, wt_hi, wt_lo, bb, invsq_l, invsq_c,
            (bf16*)l_nxt, (bf16*)c_nxt, (bf16*)l2lb, nL, nC);
        gather2_k<<<(C_ + L_) / 4, 256, 0, stream>>>(
            cptr, cdegi, c_other, (const unsigned int*)l_nxt, invsq_c, caggr,
            lptr, ldegi, l_other, (const unsigned int*)c_nxt, invsq_l, laggr, C_);
        update_k<0><<<768, 256, 0, stream>>>(
            l_cur, c_cur, laggr, caggr, (const bf16*)l2lb, wt_hi, wt_lo, bb,
            c_nxt, l_nxt, nullptr, flags);
        float* tmp = l_cur; l_cur = l_nxt; l_nxt = tmp;
        tmp = c_cur; c_cur = c_nxt; c_nxt = tmp;
    }
    // --- final iteration: c-update dead -> skip l2c MLP, c-gather, c-update;
    //     fuse output dtype conversion into the l-update epilogue ---
    mlp3_k<<<nC + nL, 256, 0, stream>>>(
        l_cur, c_cur, wt_hi, wt_lo, bb, invsq_l, invsq_c,
        (bf16*)l_nxt, (bf16*)c_nxt, (bf16*)l2lb, 0, nC);
    gather2_k<<<L_ / 4, 256, 0, stream>>>(
        cptr, cdegi, c_other, (const unsigned int*)l_nxt, invsq_c, caggr,
        lptr, ldegi, l_other, (const unsigned int*)c_nxt, invsq_l, laggr, 0);
    update_k<1><<<512, 256, 0, stream>>>(
        l_cur, c_cur, laggr, caggr, (const bf16*)l2lb, wt_hi, wt_lo, bb,
        nullptr, nullptr, d_out, flags);
}